// Round 1
// baseline (328.335 us; speedup 1.0000x reference)
//
#include <hip/hip_runtime.h>
#include <hip/hip_bf16.h>
#include <math.h>

#define B_ 4
#define T_ 4096
#define D_ 1024
#define E_ 8
#define K_ 2
#define C_ 1537   // int(T*K/E*1.5)+1

typedef short bf16x8 __attribute__((ext_vector_type(8)));
typedef float f32x4 __attribute__((ext_vector_type(4)));

__device__ __forceinline__ unsigned short f2bf(float f) {
    union { float f; unsigned int u; } c; c.f = f;
    unsigned int u = c.u;
    unsigned int r = (u + 0x7fffu + ((u >> 16) & 1u)) >> 16;
    return (unsigned short)r;
}

// ---------------------------------------------------------------------------
// Router: logits = x . Wr^T in fp64 accumulation (exact top-k ordering),
// top-2 + softmax, plus fused x -> bf16 conversion (x is fully read anyway).
// 1 wave per token, 4 tokens per block.
// ---------------------------------------------------------------------------
__global__ __launch_bounds__(256) void router_kernel(
    const float* __restrict__ x, const float* __restrict__ Wr,
    unsigned short* __restrict__ xbf, int* __restrict__ top_e,
    float* __restrict__ wbuf) {
    __shared__ float wr_s[E_ * D_];
    int tid = threadIdx.x;
    const float4* wr4 = (const float4*)Wr;
    float4* wrs4 = (float4*)wr_s;
    for (int i = tid; i < E_ * D_ / 4; i += 256) wrs4[i] = wr4[i];
    __syncthreads();

    int wave = tid >> 6, lane = tid & 63;
    int token = blockIdx.x * 4 + wave;   // 0 .. B*T-1

    const float4* xr = (const float4*)(x + (size_t)token * D_) + lane * 4;
    float xs[16];
    #pragma unroll
    for (int i = 0; i < 4; i++) {
        float4 v = xr[i];
        xs[i * 4 + 0] = v.x; xs[i * 4 + 1] = v.y;
        xs[i * 4 + 2] = v.z; xs[i * 4 + 3] = v.w;
    }

    // fused bf16 conversion of x (32 B per lane)
    unsigned short xb[16];
    #pragma unroll
    for (int i = 0; i < 16; i++) xb[i] = f2bf(xs[i]);
    uint4* dst = (uint4*)(xbf + (size_t)token * D_ + lane * 16);
    dst[0] = ((uint4*)xb)[0];
    dst[1] = ((uint4*)xb)[1];

    double acc[E_];
    #pragma unroll
    for (int e = 0; e < E_; e++) {
        const float* wp = wr_s + e * D_ + lane * 16;
        double a = 0.0;
        #pragma unroll
        for (int i = 0; i < 16; i++) a += (double)xs[i] * (double)wp[i];
        acc[e] = a;
    }
    #pragma unroll
    for (int e = 0; e < E_; e++) {
        #pragma unroll
        for (int off = 32; off > 0; off >>= 1)
            acc[e] += __shfl_down(acc[e], off, 64);
    }

    if (lane == 0) {
        int e0 = 0; double v0 = acc[0];
        #pragma unroll
        for (int e = 1; e < E_; e++) if (acc[e] > v0) { v0 = acc[e]; e0 = e; }
        int e1 = -1; double v1 = -1.0e300;
        #pragma unroll
        for (int e = 0; e < E_; e++) if (e != e0 && acc[e] > v1) { v1 = acc[e]; e1 = e; }
        double ex = exp(v1 - v0);
        float w0 = (float)(1.0 / (1.0 + ex));
        float w1 = (float)(ex / (1.0 + ex));
        top_e[token * 2 + 0] = e0;
        top_e[token * 2 + 1] = e1;
        wbuf[token * 2 + 0] = w0;
        wbuf[token * 2 + 1] = w1;
    }
}

// ---------------------------------------------------------------------------
// We[e][d][f] fp32  ->  We_t[e][f][d] bf16 (transpose so GEMM B-operand is
// k-contiguous). 64x64 tiles, 256 threads, LDS with +1 pad.
// ---------------------------------------------------------------------------
__global__ __launch_bounds__(256) void wt_kernel(const float* __restrict__ We,
                                                 unsigned short* __restrict__ wtbf) {
    __shared__ unsigned short tile[64][65];
    int e = blockIdx.x >> 8;       // 256 tiles per expert
    int t = blockIdx.x & 255;
    int d0 = (t >> 4) * 64, f0 = (t & 15) * 64;
    const float* src = We + ((size_t)e * D_ + d0) * D_ + f0;
    int tid = threadIdx.x;
    #pragma unroll
    for (int i = 0; i < 16; i++) {
        int idx = tid + i * 256;
        int r = idx >> 6, c = idx & 63;
        tile[r][c] = f2bf(src[(size_t)r * D_ + c]);
    }
    __syncthreads();
    unsigned short* dstp = wtbf + ((size_t)e * D_ + f0) * D_ + d0;
    #pragma unroll
    for (int i = 0; i < 16; i++) {
        int idx = tid + i * 256;
        int r = idx >> 6, c = idx & 63;
        dstp[(size_t)r * D_ + c] = tile[c][r];
    }
}

// ---------------------------------------------------------------------------
// Exact (t,k)-order position scan per batch. 1 block per batch.
// Produces, per (b,e): compacted slot list (slot = t*2+k) and kept count.
// ---------------------------------------------------------------------------
__global__ __launch_bounds__(256) void scan_kernel(const int* __restrict__ top_e,
                                                   int* __restrict__ list,
                                                   int* __restrict__ count) {
    int b = blockIdx.x, tid = threadIdx.x;
    const int S = T_ * K_;     // 8192 slots
    const int per = S / 256;   // 32 per thread
    __shared__ int cnt[256][E_];
    int local[E_];
    #pragma unroll
    for (int e = 0; e < E_; e++) local[e] = 0;
    const int* te = top_e + (size_t)b * S + tid * per;
    int evals[32];
    for (int i = 0; i < per; i++) { evals[i] = te[i]; local[evals[i]]++; }
    #pragma unroll
    for (int e = 0; e < E_; e++) cnt[tid][e] = local[e];
    __syncthreads();
    if (tid < E_) {
        int run = 0;
        for (int i = 0; i < 256; i++) { int v = cnt[i][tid]; cnt[i][tid] = run; run += v; }
        count[b * E_ + tid] = min(run, C_);
    }
    __syncthreads();
    int base[E_];
    #pragma unroll
    for (int e = 0; e < E_; e++) base[e] = cnt[tid][e];
    int* lst = list + (size_t)b * E_ * C_;
    for (int i = 0; i < per; i++) {
        int ev = evals[i];
        int p = base[ev]++;
        if (p < C_) lst[ev * C_ + p] = tid * per + i;
    }
}

// ---------------------------------------------------------------------------
// Grouped expert GEMM, bf16 MFMA 16x16x32, 128x128 tile, BK=32.
// A rows gathered via slot list; epilogue atomicAdds w * row into out.
// ---------------------------------------------------------------------------
#define LDA 40   // padded LDS stride (bf16 elems)

__global__ __launch_bounds__(256) void gemm_kernel(
    const unsigned short* __restrict__ xbf, const unsigned short* __restrict__ wtbf,
    const int* __restrict__ list, const int* __restrict__ count,
    const float* __restrict__ wbuf, float* __restrict__ out) {
    int cb = blockIdx.x & 7;            // 8 col blocks (N=1024/128)
    int rb = (blockIdx.x >> 3) % 13;    // 13 row blocks (ceil(C/128))
    int pe = blockIdx.x / 104;          // (b,e) pair
    int b = pe >> 3, e = pe & 7;
    int cnt = count[pe];
    int row0 = rb * 128;
    if (row0 >= cnt) return;
    int rows = min(128, cnt - row0);

    __shared__ unsigned short As[128 * LDA];
    __shared__ unsigned short Bs[128 * LDA];
    __shared__ int slots[128];

    int tid = threadIdx.x;
    if (tid < 128) slots[tid] = (tid < rows) ? list[pe * C_ + row0 + tid] : 0;
    __syncthreads();

    // staging: thread -> (row, 16B chunk); 2 rows per thread for A and B
    int chunk = tid & 3;
    int r0 = tid >> 2;        // 0..63
    int r1 = r0 + 64;
    int tA0 = slots[r0] >> 1, tA1 = slots[r1] >> 1;
    const uint4* a0 = (const uint4*)(xbf + ((size_t)b * T_ + tA0) * D_) + chunk;
    const uint4* a1 = (const uint4*)(xbf + ((size_t)b * T_ + tA1) * D_) + chunk;
    const uint4* b0 = (const uint4*)(wtbf + ((size_t)e * D_ + cb * 128 + r0) * D_) + chunk;
    const uint4* b1 = (const uint4*)(wtbf + ((size_t)e * D_ + cb * 128 + r1) * D_) + chunk;
    uint4* sa0 = (uint4*)(As + r0 * LDA + chunk * 8);
    uint4* sa1 = (uint4*)(As + r1 * LDA + chunk * 8);
    uint4* sb0 = (uint4*)(Bs + r0 * LDA + chunk * 8);
    uint4* sb1 = (uint4*)(Bs + r1 * LDA + chunk * 8);

    int wave = tid >> 6, lane = tid & 63;
    int wm = wave >> 1, wn = wave & 1;
    int quad = lane >> 4, mrow = lane & 15;
    const unsigned short* ArdBase = As + (wm * 64 + mrow) * LDA + quad * 8;
    const unsigned short* BrdBase = Bs + (wn * 64 + mrow) * LDA + quad * 8;

    f32x4 acc[4][4];
    #pragma unroll
    for (int i = 0; i < 4; i++)
        #pragma unroll
        for (int j = 0; j < 4; j++) acc[i][j] = (f32x4){0.f, 0.f, 0.f, 0.f};

    uint4 ra0 = a0[0], ra1 = a1[0], rb0 = b0[0], rb1 = b1[0];

    for (int kk = 0; kk < 32; kk++) {
        __syncthreads();               // prev compute done; LDS safe to overwrite
        *sa0 = ra0; *sa1 = ra1; *sb0 = rb0; *sb1 = rb1;
        if (kk < 31) {
            ra0 = a0[(kk + 1) * 4];
            ra1 = a1[(kk + 1) * 4];
            rb0 = b0[(kk + 1) * 4];
            rb1 = b1[(kk + 1) * 4];
        }
        __syncthreads();               // LDS tile ready
        bf16x8 af[4], bfv[4];
        #pragma unroll
        for (int i = 0; i < 4; i++)
            af[i] = *(const bf16x8*)(ArdBase + i * 16 * LDA);
        #pragma unroll
        for (int j = 0; j < 4; j++)
            bfv[j] = *(const bf16x8*)(BrdBase + j * 16 * LDA);
        #pragma unroll
        for (int i = 0; i < 4; i++)
            #pragma unroll
            for (int j = 0; j < 4; j++)
                acc[i][j] = __builtin_amdgcn_mfma_f32_16x16x32_bf16(af[i], bfv[j], acc[i][j], 0, 0, 0);
    }

    // epilogue: C/D layout col = lane&15, row = quad*4 + r
    float* outb = out + (size_t)b * T_ * D_;
    const float* wb = wbuf + (size_t)b * T_ * 2;
    int ncolbase = cb * 128 + wn * 64 + mrow;
    #pragma unroll
    for (int i = 0; i < 4; i++) {
        #pragma unroll
        for (int r = 0; r < 4; r++) {
            int m = wm * 64 + i * 16 + quad * 4 + r;
            if (m < rows) {
                int s = slots[m];
                int t = s >> 1;
                float wgt = wb[t * 2 + (s & 1)];
                float* orow = outb + (size_t)t * D_;
                #pragma unroll
                for (int j = 0; j < 4; j++)
                    atomicAdd(orow + ncolbase + j * 16, wgt * acc[i][j][r]);
            }
        }
    }
}

// ---------------------------------------------------------------------------
extern "C" void kernel_launch(void* const* d_in, const int* in_sizes, int n_in,
                              void* d_out, int out_size, void* d_ws, size_t ws_size,
                              hipStream_t stream) {
    const float* x  = (const float*)d_in[0];   // [B,T,D]
    const float* Wr = (const float*)d_in[1];   // [E,D]
    const float* We = (const float*)d_in[2];   // [E,D,D]
    float* out = (float*)d_out;                // [B,T,D]
    char* ws = (char*)d_ws;

    // ws layout (bytes)
    unsigned short* xbf  = (unsigned short*)(ws);             // 33,554,432
    unsigned short* wtbf = (unsigned short*)(ws + 33554432);  // 16,777,216
    int*   top_e = (int*)  (ws + 50331648);                   //    131,072
    float* wbuf  = (float*)(ws + 50462720);                   //    131,072
    int*   list  = (int*)  (ws + 50593792);                   //    196,736
    int*   count = (int*)  (ws + 50790528);                   //        128

    hipMemsetAsync(d_out, 0, (size_t)out_size * sizeof(float), stream);
    router_kernel<<<dim3(B_ * T_ / 4), dim3(256), 0, stream>>>(x, Wr, xbf, top_e, wbuf);
    wt_kernel<<<dim3(E_ * 256), dim3(256), 0, stream>>>(We, wtbf);
    scan_kernel<<<dim3(B_), dim3(256), 0, stream>>>(top_e, list, count);
    gemm_kernel<<<dim3(32 * 13 * 8), dim3(256), 0, stream>>>(xbf, wtbf, list, count, wbuf, out);
}